// Round 1
// 453.186 us; speedup vs baseline: 1.0969x; 1.0969x over previous
//
#include <hip/hip_runtime.h>
#include <math.h>

#define NB 8
#define NA 720
#define ND 1024
#define NH 512
#define NW 512

// DS = 4/1024 -> 1/DS = 256. S0 = -2 + DS/2 -> -S0/DS = 511.5
#define DXF 0.00390625f
#define IMG_MIN_F (-1.0f)
#define DTH_D (3.14159265358979323846 / 720.0)

#define TI 32            // i-tile rows
#define TJ 64            // j-tile cols
#define WIN 256          // staged detector window (floats); tile support <= ~77
#define NTILES 128       // (512/TI) * (512/TJ) = 16 * 8

// ---------------- Kernel 1: 11-tap conv along detector, left pad 10, *DTH ---------------
__global__ __launch_bounds__(256) void conv_kernel(const float* __restrict__ x,
                                                   const float* __restrict__ w,
                                                   float* __restrict__ y) {
    int row = blockIdx.x;                 // b*720 + a
    const float* xr = x + (size_t)row * ND;
    float* yr = y + (size_t)row * ND;

    __shared__ float s[16 + ND];
    __shared__ float wk[16];

    int tid = threadIdx.x;                // 256 threads
    if (tid < 16) s[tid] = 0.0f;          // zero pad region (need 10, do 16)
    if (tid < 11) wk[tid] = w[tid] * (float)DTH_D;

    float4 v = ((const float4*)xr)[tid];
    *(float4*)&s[16 + tid * 4] = v;
    __syncthreads();

    int d0 = tid * 4;
    float o0 = 0.f, o1 = 0.f, o2 = 0.f, o3 = 0.f;
#pragma unroll
    for (int k = 0; k < 11; ++k) {
        float wv = wk[k];
        o0 = fmaf(wv, s[6 + d0 + k], o0);
        o1 = fmaf(wv, s[7 + d0 + k], o1);
        o2 = fmaf(wv, s[8 + d0 + k], o2);
        o3 = fmaf(wv, s[9 + d0 + k], o3);
    }
    *(float4*)&yr[d0] = make_float4(o0, o1, o2, o3);
}

// ---------------- Kernel 2: per-angle tables + per-(tile,angle) window bases ---------------
// ct[a] = 256*cos(th), st[a] = 256*sin(th), cbt[tile*NA + a] = 511.5 - base(tile, a)
__global__ __launch_bounds__(256) void table_kernel(float* __restrict__ ct,
                                                    float* __restrict__ st,
                                                    float* __restrict__ cbt) {
    int idx = blockIdx.x * 256 + threadIdx.x;   // 360 blocks * 256 = 720 * 128
    int a = idx >> 7;                           // angle 0..719
    int t = idx & 127;                          // tile 0..127
    if (a >= NA) return;
    float th = (float)((a + 0.5) * DTH_D);      // THETAS f64->f32 like reference
    double thd = (double)th;
    float ca = (float)(cos(thd) * 256.0);
    float sa = (float)(sin(thd) * 256.0);
    if (t == 0) { ct[a] = ca; st[a] = sa; }

    int ibase = (t >> 3) * TI;
    int jbase = (t & 7) * TJ;
    float pi_lo = IMG_MIN_F + (ibase + 0.5f) * DXF;
    float pi_hi = IMG_MIN_F + (ibase + TI - 0.5f) * DXF;
    float pj_lo = IMG_MIN_F + (jbase + 0.5f) * DXF;
    float pj_hi = IMG_MIN_F + (jbase + TJ - 0.5f) * DXF;
    // min of u over tile corners; u = pxi*ca + pxj*sa + 511.5
    float umin = 511.5f + fminf(pi_lo * ca, pi_hi * ca) + fminf(pj_lo * sa, pj_hi * sa);
    int base = ((int)floorf(umin) - 1) & ~3;    // 16B-align for global_load_lds_dwordx4
    base = max(0, min(base, ND - WIN));         // window always inside the row
    cbt[t * NA + a] = 511.5f - (float)base;     // exact integer-valued float
}

// ---------------- Kernel 3: backprojection ---------------
// grid: 8 batches * 128 tiles = 1024 blocks (4/CU), 512 threads (8 waves).
// Tile = 32 rows (i) x 64 cols (j). lane = j, wave = i offset. 4 samples/thread.
// Double-buffered LDS window: 2 x 8 angles x 256 floats = 16 KB.

__device__ __forceinline__ void async_ld16(const float* g, float* l) {
    __builtin_amdgcn_global_load_lds((const __attribute__((address_space(1))) void*)g,
                                     (__attribute__((address_space(3))) void*)l,
                                     16, 0, 0);
}

#define WAIT_VM0_BARRIER() do { \
    asm volatile("" ::: "memory"); \
    __builtin_amdgcn_s_waitcnt(0x0F70); /* vmcnt(0) only */ \
    __builtin_amdgcn_s_barrier(); \
    asm volatile("" ::: "memory"); \
} while (0)

__global__ __launch_bounds__(512, 8) void bp_kernel(const float* __restrict__ sino,
                                                    const float* __restrict__ ct,
                                                    const float* __restrict__ st,
                                                    const float* __restrict__ cbt,
                                                    float* __restrict__ out) {
    int bid = blockIdx.x;
    // XCD-chunked swizzle (1024 % 8 == 0 -> bijective): XCD x gets logical blocks
    // [x*128, (x+1)*128) == all tiles of batch x -> its 2.95 MB sino fits the XCD L2.
    int lb = (bid & 7) * 128 + (bid >> 3);
    int b = lb >> 7;             // batch 0..7
    int tile = lb & 127;
    int ibase = (tile >> 3) * TI;
    int jbase = (tile & 7) * TJ;

    int tid = threadIdx.x;
    int lane = tid & 63;
    int wv = tid >> 6;           // 0..7

    int j = jbase + lane;
    float pxj = IMG_MIN_F + (j + 0.5f) * DXF;
    int i0 = ibase + wv;         // i_r = i0 + 8*r, r = 0..3
    float pxi0 = IMG_MIN_F + (i0 + 0.5f) * DXF;

    __shared__ float buf[2][8][WIN];   // 16 KB

    const float* srow = sino + (size_t)b * (NA * ND);
    const float* cbrow = cbt + tile * NA;

    float acc[4] = {0.f, 0.f, 0.f, 0.f};

    // stage chunk 0: wave wv stages window of angle wv (one dwordx4/lane = 1 KB)
    {
        int a = wv;
        int base = (int)(511.5f - cbrow[a]);   // exact
        const float* rp = srow + (size_t)a * ND + base + lane * 4;
        async_ld16(rp, &buf[0][wv][0]);
    }
    WAIT_VM0_BARRIER();

    for (int c = 0; c < 90; ++c) {
        int cur = c & 1;
        if (c + 1 < 90) {
            int a = (c + 1) * 8 + wv;
            int base = (int)(511.5f - cbrow[a]);
            const float* rp = srow + (size_t)a * ND + base + lane * 4;
            async_ld16(rp, &buf[cur ^ 1][wv][0]);
        }
#pragma unroll
        for (int k = 0; k < 8; ++k) {
            int a = c * 8 + k;
            float ca = ct[a];                 // uniform -> s_load
            float sa = st[a];                 // uniform -> s_load
            float cb = cbrow[a];              // uniform -> s_load (511.5 - base)
            float u = fmaf(pxj, sa, fmaf(pxi0, ca, cb));   // window-local coord, > 0
            float du = ca * 0.03125f;         // 8*DXF*ca = 8*cos
            const float* row = &buf[cur][k][0];
#pragma unroll
            for (int r = 0; r < 4; ++r) {
                int iu = (int)u;              // u in (0, WIN-2): trunc == floor
                float f = u - (float)iu;
                float v0 = row[iu];
                float v1 = row[iu + 1];
                acc[r] += v0 + f * (v1 - v0);
                u += du;
            }
        }
        WAIT_VM0_BARRIER();
    }

    float* orow = out + (size_t)b * (NH * NW);
#pragma unroll
    for (int r = 0; r < 4; ++r) {
        int i = i0 + 8 * r;
        orow[i * NW + j] = acc[r];
    }
}

extern "C" void kernel_launch(void* const* d_in, const int* in_sizes, int n_in,
                              void* d_out, int out_size, void* d_ws, size_t ws_size,
                              hipStream_t stream) {
    const float* x = (const float*)d_in[0];      // [8,1,720,1024] f32
    const float* w = (const float*)d_in[1];      // [1,1,1,11] f32
    float* out = (float*)d_out;                  // [8,1,512,512] f32
    float* ws = (float*)d_ws;

    float* sino = ws;                            // 8*720*1024 floats = 23.6 MB
    float* ct = ws + (size_t)NB * NA * ND;       // 720 floats
    float* st = ct + NA;                         // 720 floats
    float* cbt = st + NA;                        // 128*720 floats = 368 KB

    conv_kernel<<<dim3(NB * NA), dim3(256), 0, stream>>>(x, w, sino);
    table_kernel<<<dim3(360), dim3(256), 0, stream>>>(ct, st, cbt);
    bp_kernel<<<dim3(1024), dim3(512), 0, stream>>>(sino, ct, st, cbt, out);
}

// Round 2
// 336.210 us; speedup vs baseline: 1.4786x; 1.3479x over previous
//
#include <hip/hip_runtime.h>
#include <math.h>

#define NB 8
#define NA 720
#define NPAIR 360
#define ND 1024
#define NH 512
#define NW 512

// DS = 4/1024 -> 1/DS = 256. S0 = -2 + DS/2 -> -S0/DS = 511.5
#define DXF 0.00390625f
#define IMG_MIN_F (-1.0f)
#define DTH_D (3.14159265358979323846 / 720.0)

#define TI 32            // top-half i rows per block (plus 32 mirrored rows)
#define TJ 32            // j cols per block
#define WIN 64           // staged window per (row, coord-range); support <= 44+slack
#define NIT 8            // i-tiles covering top half 0..255
#define NJT 16           // j-tiles

// ---------------- Kernel 1: 11-tap conv along detector, left pad 10, *DTH ---------------
__global__ __launch_bounds__(256) void conv_kernel(const float* __restrict__ x,
                                                   const float* __restrict__ w,
                                                   float* __restrict__ y) {
    int row = blockIdx.x;                 // b*720 + a
    const float* xr = x + (size_t)row * ND;
    float* yr = y + (size_t)row * ND;

    __shared__ float s[16 + ND];
    __shared__ float wk[16];

    int tid = threadIdx.x;                // 256 threads
    if (tid < 16) s[tid] = 0.0f;
    if (tid < 11) wk[tid] = w[tid] * (float)DTH_D;

    float4 v = ((const float4*)xr)[tid];
    *(float4*)&s[16 + tid * 4] = v;
    __syncthreads();

    int d0 = tid * 4;
    float o0 = 0.f, o1 = 0.f, o2 = 0.f, o3 = 0.f;
#pragma unroll
    for (int k = 0; k < 11; ++k) {
        float wv = wk[k];
        o0 = fmaf(wv, s[6 + d0 + k], o0);
        o1 = fmaf(wv, s[7 + d0 + k], o1);
        o2 = fmaf(wv, s[8 + d0 + k], o2);
        o3 = fmaf(wv, s[9 + d0 + k], o3);
    }
    *(float4*)&yr[d0] = make_float4(o0, o1, o2, o3);
}

// ---------------- Kernel 2: per-pair tables + per-(tile,pair) window bases ---------------
// For pair p (angles p and 719-p): ca=256cos, sa=256sin of angle p.
// cbt[(tile*NPAIR + p)*2 + 0] = 511.5 - base_top   (covers u1 = +pxi*ca + pxj*sa range)
// cbt[(tile*NPAIR + p)*2 + 1] = 511.5 - base_bot   (covers u2 = -pxi*ca + pxj*sa range)
__global__ __launch_bounds__(256) void table_kernel(float* __restrict__ ct,
                                                    float* __restrict__ st,
                                                    float* __restrict__ cbt) {
    int idx = blockIdx.x * 256 + threadIdx.x;   // 360 pairs * 128 tiles = 46080
    if (idx >= NPAIR * 128) return;
    int p = idx >> 7;
    int t = idx & 127;
    float th = (float)((p + 0.5) * DTH_D);      // THETAS f64->f32 like reference
    double thd = (double)th;
    float ca = (float)(cos(thd) * 256.0);
    float sa = (float)(sin(thd) * 256.0);
    if (t == 0) { ct[p] = ca; st[p] = sa; }

    int it = t >> 4, jt = t & 15;
    int ibase = it * TI, jbase = jt * TJ;
    float pi_lo = IMG_MIN_F + (ibase + 0.5f) * DXF;
    float pi_hi = IMG_MIN_F + (ibase + TI - 0.5f) * DXF;
    float pj_lo = IMG_MIN_F + (jbase + 0.5f) * DXF;
    float pj_hi = IMG_MIN_F + (jbase + TJ - 0.5f) * DXF;
    float sj = fminf(pj_lo * sa, pj_hi * sa);
    float umin1 = 511.5f + fminf(pi_lo * ca, pi_hi * ca) + sj;
    float umin2 = 511.5f + fminf(-pi_lo * ca, -pi_hi * ca) + sj;
    int b1 = ((int)floorf(umin1) - 1) & ~3;     // 16B aligned
    int b2 = ((int)floorf(umin2) - 1) & ~3;
    b1 = max(0, min(b1, ND - WIN));
    b2 = max(0, min(b2, ND - WIN));
    float* e = cbt + ((size_t)t * NPAIR + p) * 2;
    e[0] = 511.5f - (float)b1;                  // exact integer-valued floats
    e[1] = 511.5f - (float)b2;
}

// ---------------- Kernel 3: backprojection with mirror-pair sharing ---------------
// grid: 8 batches * 128 tiles = 1024 blocks (4/CU), 512 threads (8 waves).
// Block covers rows [ibase, ibase+32) + mirrors [479-ibase..511-ibase), cols 32.
// lane = (hi<<5)|jj : jj = j offset, hi = +8 row offset. wave = row offset. r = +16.
// Per pair p: 4 LDS windows of 64 floats: [a@top | a@bot | a'@top | a'@bot].
// u1 serves row a (->accT) and row a' (->accM); u2 serves row a (->accM), a' (->accT).

__device__ __forceinline__ void async_ld16(const float* g, float* l) {
    __builtin_amdgcn_global_load_lds((const __attribute__((address_space(1))) void*)g,
                                     (__attribute__((address_space(3))) void*)l,
                                     16, 0, 0);
}

#define WAIT_VM0_BARRIER() do { \
    asm volatile("" ::: "memory"); \
    __builtin_amdgcn_s_waitcnt(0x0F70); /* vmcnt(0) only */ \
    __builtin_amdgcn_s_barrier(); \
    asm volatile("" ::: "memory"); \
} while (0)

__global__ __launch_bounds__(512, 8) void bp_kernel(const float* __restrict__ sino,
                                                    const float* __restrict__ ct,
                                                    const float* __restrict__ st,
                                                    const float* __restrict__ cbt,
                                                    float* __restrict__ out) {
    int bid = blockIdx.x;
    // XCD-chunked swizzle: XCD x -> all 128 tiles of batch x (2.95 MB sino fits its L2)
    int lb = (bid & 7) * 128 + (bid >> 3);
    int b = lb >> 7;
    int tile = lb & 127;
    int it = tile >> 4, jt = tile & 15;
    int ibase = it * TI, jbase = jt * TJ;

    int tid = threadIdx.x;
    int lane = tid & 63;
    int wv = tid >> 6;           // 0..7
    int jj = lane & 31;
    int hi = lane >> 5;          // 0/1 -> +8 rows
    int wg = lane >> 4;          // staging window group 0..3
    int wo = lane & 15;          // offset within window (x4 floats)

    int j = jbase + jj;
    float pxj = IMG_MIN_F + (j + 0.5f) * DXF;
    int i0 = ibase + wv + 8 * hi;           // +16*r
    float pxi = IMG_MIN_F + (i0 + 0.5f) * DXF;

    __shared__ float buf[2][8][4 * WIN];    // 16 KB

    const float* srow = sino + (size_t)b * (NA * ND);
    const float* cbrow = cbt + (size_t)tile * NPAIR * 2;

    float accT[2] = {0.f, 0.f};             // pixel (i, j)
    float accM[2] = {0.f, 0.f};             // pixel (511-i, j)

#define STAGE(c_, bsel_) do { \
    int p_ = (c_) * 8 + wv; \
    float cb1_ = cbrow[2 * p_]; \
    float cb2_ = cbrow[2 * p_ + 1]; \
    int b1_ = (int)(511.5f - cb1_); \
    int b2_ = (int)(511.5f - cb2_); \
    int row_ = (wg & 2) ? (719 - p_) : p_; \
    int base_ = (wg & 1) ? b2_ : b1_; \
    const float* gp_ = srow + (size_t)row_ * ND + base_ + wo * 4; \
    async_ld16(gp_, &buf[bsel_][wv][0]); \
} while (0)

    STAGE(0, 0);
    WAIT_VM0_BARRIER();

    for (int c = 0; c < 45; ++c) {
        int cur = c & 1;
        if (c + 1 < 45) STAGE(c + 1, cur ^ 1);
        const float* lb0 = &buf[cur][0][0];
#pragma unroll
        for (int k = 0; k < 8; ++k) {
            int p = c * 8 + k;
            float ca = ct[p];                  // uniform -> s_load
            float sa = st[p];
            float cb1 = cbrow[2 * p];
            float cb2 = cbrow[2 * p + 1];
            float du = ca * (16.0f * DXF);
            float u1 = fmaf(pxj, sa, fmaf(pxi, ca, cb1));    // local in a@top window
            float u2 = fmaf(pxj, sa, fmaf(pxi, -ca, cb2));   // local in a@bot window
            const float* w0 = lb0 + (k << 8);  // k*4*WIN
#pragma unroll
            for (int r = 0; r < 2; ++r) {
                int iu1 = (int)u1;             // u1 in [1, 50): trunc == floor
                float f1 = u1 - (float)iu1;
                float g1 = 1.0f - f1;
                float v0a = w0[iu1];                 // row a    @ u1 -> accT
                float v1a = w0[iu1 + 1];
                float v0p = w0[iu1 + 2 * WIN];       // row a'   @ u1 -> accM
                float v1p = w0[iu1 + 2 * WIN + 1];
                accT[r] = fmaf(v0a, g1, accT[r]);
                accT[r] = fmaf(v1a, f1, accT[r]);
                accM[r] = fmaf(v0p, g1, accM[r]);
                accM[r] = fmaf(v1p, f1, accM[r]);

                int iu2 = (int)u2;
                float f2 = u2 - (float)iu2;
                float g2 = 1.0f - f2;
                const float* wB = w0 + WIN;
                float x0a = wB[iu2];                 // row a    @ u2 -> accM
                float x1a = wB[iu2 + 1];
                float x0p = wB[iu2 + 2 * WIN];       // row a'   @ u2 -> accT
                float x1p = wB[iu2 + 2 * WIN + 1];
                accM[r] = fmaf(x0a, g2, accM[r]);
                accM[r] = fmaf(x1a, f2, accM[r]);
                accT[r] = fmaf(x0p, g2, accT[r]);
                accT[r] = fmaf(x1p, f2, accT[r]);

                u1 += du;
                u2 -= du;
            }
        }
        WAIT_VM0_BARRIER();
    }

    float* orow = out + (size_t)b * (NH * NW);
#pragma unroll
    for (int r = 0; r < 2; ++r) {
        int i = i0 + 16 * r;
        orow[i * NW + j] = accT[r];
        orow[(511 - i) * NW + j] = accM[r];
    }
#undef STAGE
}

extern "C" void kernel_launch(void* const* d_in, const int* in_sizes, int n_in,
                              void* d_out, int out_size, void* d_ws, size_t ws_size,
                              hipStream_t stream) {
    const float* x = (const float*)d_in[0];      // [8,1,720,1024] f32
    const float* w = (const float*)d_in[1];      // [1,1,1,11] f32
    float* out = (float*)d_out;                  // [8,1,512,512] f32
    float* ws = (float*)d_ws;

    float* sino = ws;                            // 8*720*1024 floats = 23.6 MB
    float* ct = ws + (size_t)NB * NA * ND;       // 360 floats
    float* st = ct + NPAIR;                      // 360 floats
    float* cbt = st + NPAIR;                     // 128*360*2 floats = 368 KB

    conv_kernel<<<dim3(NB * NA), dim3(256), 0, stream>>>(x, w, sino);
    table_kernel<<<dim3(180), dim3(256), 0, stream>>>(ct, st, cbt);
    bp_kernel<<<dim3(1024), dim3(512), 0, stream>>>(sino, ct, st, cbt, out);
}

// Round 3
// 284.306 us; speedup vs baseline: 1.7485x; 1.1826x over previous
//
#include <hip/hip_runtime.h>
#include <math.h>

#define NB 8
#define NA 720
#define NPAIR 360
#define ND 1024
#define NH 512
#define NW 512

// DS = 4/1024 -> 1/DS = 256. S0 = -2 + DS/2 -> -S0/DS = 511.5
#define DXF 0.00390625f
#define IMG_MIN_F (-1.0f)
#define DTH_D (3.14159265358979323846 / 720.0)

#define TI 32            // top-half i rows per block (plus 32 mirrored rows)
#define TJ 32            // j cols per block
#define WIN 64           // staged window per (row, coord-range); support <= 44+slack

typedef float f32x2 __attribute__((ext_vector_type(2)));

// ---------------- Kernel 1: 11-tap conv along detector, left pad 10, *DTH ---------------
__global__ __launch_bounds__(256) void conv_kernel(const float* __restrict__ x,
                                                   const float* __restrict__ w,
                                                   float* __restrict__ y) {
    int row = blockIdx.x;                 // b*720 + a
    const float* xr = x + (size_t)row * ND;
    float* yr = y + (size_t)row * ND;

    __shared__ float s[16 + ND];
    __shared__ float wk[16];

    int tid = threadIdx.x;                // 256 threads
    if (tid < 16) s[tid] = 0.0f;
    if (tid < 11) wk[tid] = w[tid] * (float)DTH_D;

    float4 v = ((const float4*)xr)[tid];
    *(float4*)&s[16 + tid * 4] = v;
    __syncthreads();

    int d0 = tid * 4;
    float o0 = 0.f, o1 = 0.f, o2 = 0.f, o3 = 0.f;
#pragma unroll
    for (int k = 0; k < 11; ++k) {
        float wv = wk[k];
        o0 = fmaf(wv, s[6 + d0 + k], o0);
        o1 = fmaf(wv, s[7 + d0 + k], o1);
        o2 = fmaf(wv, s[8 + d0 + k], o2);
        o3 = fmaf(wv, s[9 + d0 + k], o3);
    }
    *(float4*)&yr[d0] = make_float4(o0, o1, o2, o3);
}

// ---------------- Kernel 2: per-pair tables + per-(tile,pair) window bases ---------------
__global__ __launch_bounds__(256) void table_kernel(float* __restrict__ ct,
                                                    float* __restrict__ st,
                                                    float* __restrict__ cbt) {
    int idx = blockIdx.x * 256 + threadIdx.x;   // 360 pairs * 128 tiles = 46080
    if (idx >= NPAIR * 128) return;
    int p = idx >> 7;
    int t = idx & 127;
    float th = (float)((p + 0.5) * DTH_D);      // THETAS f64->f32 like reference
    double thd = (double)th;
    float ca = (float)(cos(thd) * 256.0);
    float sa = (float)(sin(thd) * 256.0);
    if (t == 0) { ct[p] = ca; st[p] = sa; }

    int it = t >> 4, jt = t & 15;
    int ibase = it * TI, jbase = jt * TJ;
    float pi_lo = IMG_MIN_F + (ibase + 0.5f) * DXF;
    float pi_hi = IMG_MIN_F + (ibase + TI - 0.5f) * DXF;
    float pj_lo = IMG_MIN_F + (jbase + 0.5f) * DXF;
    float pj_hi = IMG_MIN_F + (jbase + TJ - 0.5f) * DXF;
    float sj = fminf(pj_lo * sa, pj_hi * sa);
    float umin1 = 511.5f + fminf(pi_lo * ca, pi_hi * ca) + sj;
    float umin2 = 511.5f + fminf(-pi_lo * ca, -pi_hi * ca) + sj;
    int b1 = ((int)floorf(umin1) - 1) & ~3;     // 16B aligned
    int b2 = ((int)floorf(umin2) - 1) & ~3;
    b1 = max(0, min(b1, ND - WIN));
    b2 = max(0, min(b2, ND - WIN));
    float* e = cbt + ((size_t)t * NPAIR + p) * 2;
    e[0] = 511.5f - (float)b1;                  // exact integer-valued floats
    e[1] = 511.5f - (float)b2;
}

// ---------------- Kernel 3: backprojection, mirror pairs + packed-FMA lerp ---------------
__device__ __forceinline__ void async_ld16(const float* g, float* l) {
    __builtin_amdgcn_global_load_lds((const __attribute__((address_space(1))) void*)g,
                                     (__attribute__((address_space(3))) void*)l,
                                     16, 0, 0);
}

#define WAIT_VM0_BARRIER() do { \
    asm volatile("" ::: "memory"); \
    __builtin_amdgcn_s_waitcnt(0x0F70); /* vmcnt(0) only */ \
    __builtin_amdgcn_s_barrier(); \
    asm volatile("" ::: "memory"); \
} while (0)

// acc += (v0,v1) * (g,f)  -- one VOP3P instruction for two lerp taps
#define PK_FMA(acc_, v01_, gf_) \
    asm("v_pk_fma_f32 %0, %1, %2, %0" : "+v"(acc_) : "v"(v01_), "v"(gf_))

__global__ __launch_bounds__(512, 8) void bp_kernel(const float* __restrict__ sino,
                                                    const float* __restrict__ ct,
                                                    const float* __restrict__ st,
                                                    const float* __restrict__ cbt,
                                                    float* __restrict__ out) {
    int bid = blockIdx.x;
    // XCD-chunked swizzle: XCD x -> all 128 tiles of batch x (2.95 MB sino fits its L2)
    int lb = (bid & 7) * 128 + (bid >> 3);
    int b = lb >> 7;
    int tile = lb & 127;
    int it = tile >> 4, jt = tile & 15;
    int ibase = it * TI, jbase = jt * TJ;

    int tid = threadIdx.x;
    int lane = tid & 63;
    int wv = tid >> 6;           // 0..7
    int jj = lane & 31;
    int hi = lane >> 5;          // 0/1 -> +8 rows
    int wg = lane >> 4;          // staging window group 0..3
    int wo = lane & 15;          // offset within window (x4 floats)

    int j = jbase + jj;
    float pxj = IMG_MIN_F + (j + 0.5f) * DXF;
    int i0 = ibase + wv + 8 * hi;           // +16*r
    float pxi = IMG_MIN_F + (i0 + 0.5f) * DXF;

    __shared__ float buf[2][8][4 * WIN];    // 16 KB

    const float* srow = sino + (size_t)b * (NA * ND);
    const float* cbrow = cbt + (size_t)tile * NPAIR * 2;

    // packed accumulator halves: .x ~ v0*g taps, .y ~ v1*f taps
    f32x2 aT1[2], aM1[2], aT2[2], aM2[2];
#pragma unroll
    for (int r = 0; r < 2; ++r) {
        aT1[r] = (f32x2){0.f, 0.f}; aM1[r] = (f32x2){0.f, 0.f};
        aT2[r] = (f32x2){0.f, 0.f}; aM2[r] = (f32x2){0.f, 0.f};
    }

#define STAGE(c_, bsel_) do { \
    int p_ = (c_) * 8 + wv; \
    float cb1_ = cbrow[2 * p_]; \
    float cb2_ = cbrow[2 * p_ + 1]; \
    int b1_ = (int)(511.5f - cb1_); \
    int b2_ = (int)(511.5f - cb2_); \
    int row_ = (wg & 2) ? (719 - p_) : p_; \
    int base_ = (wg & 1) ? b2_ : b1_; \
    const float* gp_ = srow + (size_t)row_ * ND + base_ + wo * 4; \
    async_ld16(gp_, &buf[bsel_][wv][0]); \
} while (0)

    STAGE(0, 0);
    WAIT_VM0_BARRIER();

    for (int c = 0; c < 45; ++c) {
        int cur = c & 1;
        if (c + 1 < 45) STAGE(c + 1, cur ^ 1);
        const float* lb0 = &buf[cur][0][0];
#pragma unroll
        for (int k = 0; k < 8; ++k) {
            int p = c * 8 + k;
            float ca = ct[p];                  // uniform -> s_load
            float sa = st[p];
            float cb1 = cbrow[2 * p];
            float cb2 = cbrow[2 * p + 1];
            float du = ca * (16.0f * DXF);
            float u1 = fmaf(pxj, sa, fmaf(pxi, ca, cb1));    // local in a@top window
            float u2 = fmaf(pxj, sa, fmaf(pxi, -ca, cb2));   // local in a@bot window
            const float* w0 = lb0 + (k << 8);  // k*4*WIN
#pragma unroll
            for (int r = 0; r < 2; ++r) {
                // ---- u1 serves row a (->T) and row a' (->M), windows +0 / +128
                int iu1 = (int)u1;                    // u1 in [1,50): trunc == floor
                float f1 = __builtin_amdgcn_fractf(u1);
                f32x2 gf1; gf1.x = 1.0f - f1; gf1.y = f1;
                f32x2 va, vp;
                va.x = w0[iu1];       va.y = w0[iu1 + 1];        // ds_read2 (0,1)
                vp.x = w0[iu1 + 128]; vp.y = w0[iu1 + 129];      // ds_read2 (128,129)
                PK_FMA(aT1[r], va, gf1);
                PK_FMA(aM1[r], vp, gf1);

                // ---- u2 serves row a (->M) and row a' (->T), windows +64 / +192
                int iu2 = (int)u2;
                float f2 = __builtin_amdgcn_fractf(u2);
                f32x2 gf2; gf2.x = 1.0f - f2; gf2.y = f2;
                const float* wB = w0 + WIN;
                f32x2 xa, xp;
                xa.x = wB[iu2];       xa.y = wB[iu2 + 1];
                xp.x = wB[iu2 + 128]; xp.y = wB[iu2 + 129];
                PK_FMA(aM2[r], xa, gf2);
                PK_FMA(aT2[r], xp, gf2);

                u1 += du;
                u2 -= du;
            }
        }
        WAIT_VM0_BARRIER();
    }

    float* orow = out + (size_t)b * (NH * NW);
#pragma unroll
    for (int r = 0; r < 2; ++r) {
        int i = i0 + 16 * r;
        float accT = (aT1[r].x + aT1[r].y) + (aT2[r].x + aT2[r].y);
        float accM = (aM1[r].x + aM1[r].y) + (aM2[r].x + aM2[r].y);
        orow[i * NW + j] = accT;
        orow[(511 - i) * NW + j] = accM;
    }
#undef STAGE
}

extern "C" void kernel_launch(void* const* d_in, const int* in_sizes, int n_in,
                              void* d_out, int out_size, void* d_ws, size_t ws_size,
                              hipStream_t stream) {
    const float* x = (const float*)d_in[0];      // [8,1,720,1024] f32
    const float* w = (const float*)d_in[1];      // [1,1,1,11] f32
    float* out = (float*)d_out;                  // [8,1,512,512] f32
    float* ws = (float*)d_ws;

    float* sino = ws;                            // 8*720*1024 floats = 23.6 MB
    float* ct = ws + (size_t)NB * NA * ND;       // 360 floats
    float* st = ct + NPAIR;                      // 360 floats
    float* cbt = st + NPAIR;                     // 128*360*2 floats = 368 KB

    conv_kernel<<<dim3(NB * NA), dim3(256), 0, stream>>>(x, w, sino);
    table_kernel<<<dim3(180), dim3(256), 0, stream>>>(ct, st, cbt);
    bp_kernel<<<dim3(1024), dim3(512), 0, stream>>>(sino, ct, st, cbt, out);
}

// Round 4
// 281.498 us; speedup vs baseline: 1.7659x; 1.0100x over previous
//
#include <hip/hip_runtime.h>
#include <math.h>

#define NB 8
#define NA 720
#define NPAIR 360
#define ND 1024
#define NH 512
#define NW 512

// DS = 4/1024 -> 1/DS = 256. S0 = -2 + DS/2 -> -S0/DS = 511.5
#define DXF 0.00390625f
#define IMG_MIN_F (-1.0f)
#define DTH_D (3.14159265358979323846 / 720.0)

#define TI 32            // top-half i rows per block (plus 32 mirrored rows)
#define TJ 32            // j cols per block
#define WIN 64           // staged window per (row, coord-range); support <= 44+slack

typedef float f32x2 __attribute__((ext_vector_type(2)));

// ---------------- Kernel 1: 11-tap conv along detector, left pad 10, *DTH ---------------
__global__ __launch_bounds__(256) void conv_kernel(const float* __restrict__ x,
                                                   const float* __restrict__ w,
                                                   float* __restrict__ y) {
    int row = blockIdx.x;                 // b*720 + a
    const float* xr = x + (size_t)row * ND;
    float* yr = y + (size_t)row * ND;

    __shared__ float s[16 + ND];
    __shared__ float wk[16];

    int tid = threadIdx.x;                // 256 threads
    if (tid < 16) s[tid] = 0.0f;
    if (tid < 11) wk[tid] = w[tid] * (float)DTH_D;

    float4 v = ((const float4*)xr)[tid];
    *(float4*)&s[16 + tid * 4] = v;
    __syncthreads();

    int d0 = tid * 4;
    float o0 = 0.f, o1 = 0.f, o2 = 0.f, o3 = 0.f;
#pragma unroll
    for (int k = 0; k < 11; ++k) {
        float wv = wk[k];
        o0 = fmaf(wv, s[6 + d0 + k], o0);
        o1 = fmaf(wv, s[7 + d0 + k], o1);
        o2 = fmaf(wv, s[8 + d0 + k], o2);
        o3 = fmaf(wv, s[9 + d0 + k], o3);
    }
    *(float4*)&yr[d0] = make_float4(o0, o1, o2, o3);
}

// ---------------- Kernel 2: per-pair tables + per-(tile,pair) window bases ---------------
__global__ __launch_bounds__(256) void table_kernel(float* __restrict__ ct,
                                                    float* __restrict__ st,
                                                    float* __restrict__ cbt) {
    int idx = blockIdx.x * 256 + threadIdx.x;   // 360 pairs * 128 tiles = 46080
    if (idx >= NPAIR * 128) return;
    int p = idx >> 7;
    int t = idx & 127;
    float th = (float)((p + 0.5) * DTH_D);      // THETAS f64->f32 like reference
    double thd = (double)th;
    float ca = (float)(cos(thd) * 256.0);
    float sa = (float)(sin(thd) * 256.0);
    if (t == 0) { ct[p] = ca; st[p] = sa; }

    int it = t >> 4, jt = t & 15;
    int ibase = it * TI, jbase = jt * TJ;
    float pi_lo = IMG_MIN_F + (ibase + 0.5f) * DXF;
    float pi_hi = IMG_MIN_F + (ibase + TI - 0.5f) * DXF;
    float pj_lo = IMG_MIN_F + (jbase + 0.5f) * DXF;
    float pj_hi = IMG_MIN_F + (jbase + TJ - 0.5f) * DXF;
    float sj = fminf(pj_lo * sa, pj_hi * sa);
    float umin1 = 511.5f + fminf(pi_lo * ca, pi_hi * ca) + sj;
    float umin2 = 511.5f + fminf(-pi_lo * ca, -pi_hi * ca) + sj;
    int b1 = ((int)floorf(umin1) - 1) & ~3;     // 16B aligned source base
    int b2 = ((int)floorf(umin2) - 1) & ~3;
    b1 = max(0, min(b1, ND - WIN));
    b2 = max(0, min(b2, ND - WIN));
    float* e = cbt + ((size_t)t * NPAIR + p) * 2;
    e[0] = 511.5f - (float)b1;                  // exact integer-valued floats
    e[1] = 511.5f - (float)b2;
}

// ---------------- Kernel 3: backprojection, interleaved windows + ds_read2_b64 ---------------
// LDS per pair k: 256 floats = [W1: interleave(a@top, a'@top) 128f | W2: interleave(a@bot, a'@bot) 128f]
// One u-sample reads (a[iu], a'[iu], a[iu+1], a'[iu+1]) = one ds_read2_b64 (merged 2x float2).
// Lerp: accPair += (a[iu],a'[iu])*g + (a[iu+1],a'[iu+1])*f via 2x v_pk_fma_f32 op_sel broadcast.

// acc.(lo,hi) += v01.(lo,hi) * gf.lo   (broadcast low half of gf)
#define PK_FMA_LO(acc_, v01_, gf_) \
    asm("v_pk_fma_f32 %0, %1, %2, %0 op_sel_hi:[1,0,1]" : "+v"(acc_) : "v"(v01_), "v"(gf_))
// acc.(lo,hi) += v01.(lo,hi) * gf.hi   (broadcast high half of gf)
#define PK_FMA_HI(acc_, v01_, gf_) \
    asm("v_pk_fma_f32 %0, %1, %2, %0 op_sel:[0,1,0]" : "+v"(acc_) : "v"(v01_), "v"(gf_))

__global__ __launch_bounds__(512, 8) void bp_kernel(const float* __restrict__ sino,
                                                    const float* __restrict__ ct,
                                                    const float* __restrict__ st,
                                                    const float* __restrict__ cbt,
                                                    float* __restrict__ out) {
    int bid = blockIdx.x;
    // XCD-chunked swizzle: XCD x -> all 128 tiles of batch x (2.95 MB sino fits its L2)
    int lb = (bid & 7) * 128 + (bid >> 3);
    int b = lb >> 7;
    int tile = lb & 127;
    int it = tile >> 4, jt = tile & 15;
    int ibase = it * TI, jbase = jt * TJ;

    int tid = threadIdx.x;
    int lane = tid & 63;
    int wv = tid >> 6;           // 0..7 -> stages pair c*8+wv
    int jj = lane & 31;
    int hi = lane >> 5;          // 0/1 -> +8 rows
    int sel = lane >> 5;         // staging: 0 -> W1(top), 1 -> W2(bot)
    int m = lane & 31;           // staging element index (2 floats each)

    int j = jbase + jj;
    float pxj = IMG_MIN_F + (j + 0.5f) * DXF;
    int i0 = ibase + wv + 8 * hi;           // +16*r
    float pxi = IMG_MIN_F + (i0 + 0.5f) * DXF;

    __shared__ float buf[2][8][256];        // 16 KB

    const float* srow = sino + (size_t)b * (NA * ND);
    const float* cbrow = cbt + (size_t)tile * NPAIR * 2;

    // acc pairs: aU1[r] = (T, M) fed by u1; aU2[r] = (M, T) fed by u2
    f32x2 aU1[2], aU2[2];
#pragma unroll
    for (int r = 0; r < 2; ++r) { aU1[r] = (f32x2){0.f, 0.f}; aU2[r] = (f32x2){0.f, 0.f}; }

    float2 stA, stB;   // staged global data (row a, row a')

#define LOADREGS(c_) do { \
    int p_ = (c_) * 8 + wv; \
    float cb1_ = cbrow[2 * p_]; \
    float cb2_ = cbrow[2 * p_ + 1]; \
    int base_ = (int)(511.5f - (sel ? cb2_ : cb1_)); \
    const float* pa_ = srow + (size_t)p_ * ND + base_ + 2 * m; \
    const float* pb_ = srow + (size_t)(719 - p_) * ND + base_ + 2 * m; \
    stA = *(const float2*)pa_; \
    stB = *(const float2*)pb_; \
} while (0)

#define DSWRITE(bsel_) do { \
    float* W_ = &buf[bsel_][wv][sel * 128 + 4 * m]; \
    W_[0] = stA.x; W_[1] = stB.x; W_[2] = stA.y; W_[3] = stB.y; \
} while (0)

    LOADREGS(0);
    DSWRITE(0);
    __syncthreads();

    for (int c = 0; c < 45; ++c) {
        int cur = c & 1;
        if (c + 1 < 45) LOADREGS(c + 1);    // issue early; latency hides under compute
        const float* lb0 = &buf[cur][0][0];
#pragma unroll
        for (int k = 0; k < 8; ++k) {
            int p = c * 8 + k;
            float ca = ct[p];                  // uniform -> s_load
            float sa = st[p];
            float cb1 = cbrow[2 * p];
            float cb2 = cbrow[2 * p + 1];
            float du = ca * (16.0f * DXF);
            float u1 = fmaf(pxj, sa, fmaf(pxi, ca, cb1));    // local in W1
            float u2 = fmaf(pxj, sa, fmaf(pxi, -ca, cb2));   // local in W2
            const float* w1 = lb0 + (k << 8);        // interleaved top windows
            const float* w2 = w1 + 128;              // interleaved bot windows
#pragma unroll
            for (int r = 0; r < 2; ++r) {
                // ---- u1: rows (a -> T, a' -> M)
                int iu1 = (int)u1;                    // u1 in [1,50): trunc == floor
                float f1 = __builtin_amdgcn_fractf(u1);
                f32x2 gf1; gf1.x = 1.0f - f1; gf1.y = f1;
                const float* q1 = w1 + 2 * iu1;
                f32x2 qa = *(const f32x2*)q1;         // (a[iu], a'[iu])    } merge ->
                f32x2 qb = *(const f32x2*)(q1 + 2);   // (a[iu+1], a'[iu+1]) ds_read2_b64
                PK_FMA_LO(aU1[r], qa, gf1);
                PK_FMA_HI(aU1[r], qb, gf1);

                // ---- u2: rows (a -> M, a' -> T)
                int iu2 = (int)u2;
                float f2 = __builtin_amdgcn_fractf(u2);
                f32x2 gf2; gf2.x = 1.0f - f2; gf2.y = f2;
                const float* q2 = w2 + 2 * iu2;
                f32x2 xa = *(const f32x2*)q2;
                f32x2 xb = *(const f32x2*)(q2 + 2);
                PK_FMA_LO(aU2[r], xa, gf2);
                PK_FMA_HI(aU2[r], xb, gf2);

                u1 += du;
                u2 -= du;
            }
        }
        if (c + 1 < 45) DSWRITE(cur ^ 1);   // waits vmcnt automatically
        __syncthreads();
    }

    float* orow = out + (size_t)b * (NH * NW);
#pragma unroll
    for (int r = 0; r < 2; ++r) {
        int i = i0 + 16 * r;
        float accT = aU1[r].x + aU2[r].y;
        float accM = aU1[r].y + aU2[r].x;
        orow[i * NW + j] = accT;
        orow[(511 - i) * NW + j] = accM;
    }
#undef LOADREGS
#undef DSWRITE
}

extern "C" void kernel_launch(void* const* d_in, const int* in_sizes, int n_in,
                              void* d_out, int out_size, void* d_ws, size_t ws_size,
                              hipStream_t stream) {
    const float* x = (const float*)d_in[0];      // [8,1,720,1024] f32
    const float* w = (const float*)d_in[1];      // [1,1,1,11] f32
    float* out = (float*)d_out;                  // [8,1,512,512] f32
    float* ws = (float*)d_ws;

    float* sino = ws;                            // 8*720*1024 floats = 23.6 MB
    float* ct = ws + (size_t)NB * NA * ND;       // 360 floats
    float* st = ct + NPAIR;                      // 360 floats
    float* cbt = st + NPAIR;                     // 128*360*2 floats = 368 KB

    conv_kernel<<<dim3(NB * NA), dim3(256), 0, stream>>>(x, w, sino);
    table_kernel<<<dim3(180), dim3(256), 0, stream>>>(ct, st, cbt);
    bp_kernel<<<dim3(1024), dim3(512), 0, stream>>>(sino, ct, st, cbt, out);
}